// Round 1
// baseline (347.905 us; speedup 1.0000x reference)
//
#include <hip/hip_runtime.h>
#include <math.h>

#define NTOK 4096
#define CCH  64
#define LOG2E 1.4426950408889634f
#define NSPLIT 4   // KV-split ways

typedef __attribute__((ext_vector_type(8)))  short bf16x8;   // 8 bf16 = 4 VGPRs
typedef __attribute__((ext_vector_type(4)))  float f32x4;
typedef __attribute__((ext_vector_type(16))) float f32x16;
typedef __attribute__((ext_vector_type(2)))  unsigned int uint32x2;

__device__ __forceinline__ unsigned short f2bf_rne(float f) {
    unsigned int u = __float_as_uint(f);
    u += 0x7FFFu + ((u >> 16) & 1u);
    return (unsigned short)(u >> 16);
}
__device__ __forceinline__ float bf2f(unsigned short u) {
    return __uint_as_float(((unsigned int)u) << 16);
}

// ---------------------------------------------------------------------------
// Kernel 1: MFMA projections (round-5 proven, unchanged). One GEMM per
// (b, 64-token tile): D[80x64] = [wv ; wq*log2e ; wk] * x_tile.
// Outputs qt/kt[b][n][8] (q pre-scaled by log2e) and
// vbf[b][c][tile*64 + sigma(nu)], sigma(nu) = 4*(nu&15) + (nu>>4).
// ---------------------------------------------------------------------------
__global__ __launch_bounds__(256) void proj_kernel(
    const float* __restrict__ x,
    const float* __restrict__ wq, const float* __restrict__ bq,
    const float* __restrict__ wk, const float* __restrict__ bk,
    const float* __restrict__ wv, const float* __restrict__ bv,
    unsigned short* __restrict__ qt, unsigned short* __restrict__ kt,
    unsigned short* __restrict__ vbf)
{
    __shared__ unsigned short xsb[64 * 68];  // [n][c] bf16 (B^T storage)
    __shared__ unsigned short wa[80 * 68];   // [m][c] bf16 (A storage)
    __shared__ unsigned short vtmp[64 * 66]; // [c][sigma(n)]
    __shared__ float bb[80];

    const int t  = threadIdx.x;
    const int b  = blockIdx.x >> 6;
    const int n0 = (blockIdx.x & 63) << 6;

    const int lane = t & 63;
    const int w    = t >> 6;
    const int l15  = lane & 15;
    const int g    = lane >> 4;

    {
        const int n  = t & 63;
        const int c0 = t >> 6;
        #pragma unroll
        for (int r = 0; r < 16; ++r) {
            const int c = c0 + 4 * r;
            xsb[n * 68 + c] = f2bf_rne(x[((size_t)(b * CCH + c)) * NTOK + n0 + n]);
        }
    }
    #pragma unroll
    for (int r = 0; r < 16; ++r) {
        const int i = t + 256 * r;
        wa[(i >> 6) * 68 + (i & 63)] = f2bf_rne(wv[i]);
    }
    {
        const int i0 = t, i1 = t + 256;
        wa[(64 + (i0 >> 6)) * 68 + (i0 & 63)] = f2bf_rne(wq[i0] * LOG2E);
        wa[(64 + (i1 >> 6)) * 68 + (i1 & 63)] = f2bf_rne(wq[i1] * LOG2E);
        wa[(72 + (i0 >> 6)) * 68 + (i0 & 63)] = f2bf_rne(wk[i0]);
        wa[(72 + (i1 >> 6)) * 68 + (i1 & 63)] = f2bf_rne(wk[i1]);
    }
    if (t < 80) {
        float bias;
        if (t < 64)      bias = bv[t];
        else if (t < 72) bias = bq[t - 64] * LOG2E;
        else             bias = bk[t - 72];
        bb[t] = bias;
    }
    __syncthreads();

    f32x4 acc[5];
    #pragma unroll
    for (int mt = 0; mt < 5; ++mt) acc[mt] = (f32x4){0.f, 0.f, 0.f, 0.f};
    #pragma unroll
    for (int kc = 0; kc < 2; ++kc) {
        const bf16x8 bx = *(const bf16x8*)&xsb[(w * 16 + l15) * 68 + kc * 32 + g * 8];
        #pragma unroll
        for (int mt = 0; mt < 5; ++mt) {
            const bf16x8 aw = *(const bf16x8*)&wa[(mt * 16 + l15) * 68 + kc * 32 + g * 8];
            acc[mt] = __builtin_amdgcn_mfma_f32_16x16x32_bf16(aw, bx, acc[mt], 0, 0, 0);
        }
    }

    const int n = w * 16 + l15;
    #pragma unroll
    for (int mt = 0; mt < 4; ++mt) {
        #pragma unroll
        for (int r = 0; r < 4; ++r) {
            const int c = mt * 16 + g * 4 + r;
            vtmp[c * 66 + 4 * l15 + w] = f2bf_rne(acc[mt][r] + bb[c]);
        }
    }
    {
        unsigned short vals[4];
        #pragma unroll
        for (int r = 0; r < 4; ++r)
            vals[r] = f2bf_rne(acc[4][r] + bb[64 + g * 4 + r]);
        const unsigned int lo = (unsigned int)vals[0] | ((unsigned int)vals[1] << 16);
        const unsigned int hi = (unsigned int)vals[2] | ((unsigned int)vals[3] << 16);
        unsigned short* dst = ((g < 2) ? qt : kt) +
                              ((size_t)(b * NTOK + n0 + n)) * 8 + (g & 1) * 4;
        *(uint32x2*)dst = (uint32x2){lo, hi};
    }
    __syncthreads();

    {
        const int c = t >> 2;
        const int q = t & 3;
        unsigned short* dst = vbf + ((size_t)(b * CCH + c)) * NTOK + n0 + q * 16;
        *(bf16x8*)dst       = *(const bf16x8*)&vtmp[c * 66 + q * 16];
        *(bf16x8*)(dst + 8) = *(const bf16x8*)&vtmp[c * 66 + q * 16 + 8];
    }
}

// ---------------------------------------------------------------------------
// Kernel 2: MFMA flash attention, KV-split 4 ways. Round-12 changes (LDS-pipe
// theory: ds ops were ~59% of kernel cycles, between 2 barriers/iter):
//  1. V is NOT staged through LDS anymore. vbf is already sigma-permuted and
//     XCD-L2-resident (bid%8 == b == XCD id => batch b's working set lives in
//     XCD b's L2), so PV's A-fragment loads straight from global with a
//     one-iteration register prefetch (issued right after the PV that consumed
//     the previous tile; consumed after the next barrier => ~full QK+exp+
//     barrier latency to hide the L2 hit). Removes 2 ds_write_b128 + 4
//     ds_read_b128 per wave-iter: LDS pipe per block-iter 576 -> 288 cyc.
//  2. ps is double-buffered (parity it&1) => ONE __syncthreads per iteration
//     (write-after-read across iterations is resolved by the buffer swap;
//     any wave reaching barrier(i+1) has already drained its PV(i) ds_reads).
//     Total LDS stays 22528 B (2 x 64 x 88 ushort) => occupancy unchanged.
//  3. s_setprio(1) around both MFMA clusters (T5: waves are now genuinely
//     phase-staggered with a single barrier; measured +4-7% on attn).
// ---------------------------------------------------------------------------
__global__ __launch_bounds__(256, 6) void attn_kernel(
    const unsigned short* __restrict__ qt, const unsigned short* __restrict__ kt,
    const unsigned short* __restrict__ vbf,
    unsigned short* __restrict__ opart, float* __restrict__ lpart, int B)
{
    __shared__ unsigned short ps[2][64 * 88];  // [buf][m][n'] bf16 P, dbuf

    const int t    = threadIdx.x;
    const int lane = t & 63;
    const int w    = t >> 6;
    const int bid  = blockIdx.x;
    const int b    = bid % B;                 // == bid & 7 for B=8 -> XCD id
    const int p    = (bid / B) % NSPLIT;
    const int m0   = (bid / (B * NSPLIT)) << 6;

    const int l15 = lane & 15;
    const int g   = lane >> 4;
    const int l31 = lane & 31;
    const int h   = lane >> 5;

    const int NIT     = 64 / NSPLIT;        // 16 KV tiles per block
    const int itStart = p * NIT;

    // ---- Q A-fragment direct from global (k>=8 rows zero) ----
    bf16x8 a_q = {};
    if (g == 0)
        a_q = *(const bf16x8*)&qt[((size_t)(b * NTOK + m0 + w * 16 + l15)) * 8];

    // ---- V A-fragment global source: c = (w>>1)*32 + l31, n' = kc*16 + h*8.
    //      Exactly the bytes the old vs[c*88 + kc*16 + h*8] read, since vs was
    //      a verbatim copy of this vbf range. L2-hot (XCD-local working set).
    const int cv = (w >> 1) * 32 + l31;
    const unsigned short* vp = vbf + ((size_t)(b * CCH + cv)) * NTOK
                                   + itStart * 64 + h * 8;

    // ---- K fragment source (only g==0 lanes load; others stay zero) ----
    const unsigned short* ksrc = kt + ((size_t)(b * NTOK + itStart * 64 + l15)) * 8;

    // ---- prefetch iteration 0 ----
    bf16x8 av0 = *(const bf16x8*)(vp);
    bf16x8 av1 = *(const bf16x8*)(vp + 16);
    bf16x8 av2 = *(const bf16x8*)(vp + 32);
    bf16x8 av3 = *(const bf16x8*)(vp + 48);
    bf16x8 kr0 = {}, kr1 = {}, kr2 = {}, kr3 = {};
    if (g == 0) {
        kr0 = *(const bf16x8*)(ksrc);
        kr1 = *(const bf16x8*)(ksrc + 128);   // +16 tokens * 8
        kr2 = *(const bf16x8*)(ksrc + 256);
        kr3 = *(const bf16x8*)(ksrc + 384);
    }

    f32x16 oacc;
    #pragma unroll
    for (int i = 0; i < 16; ++i) oacc[i] = 0.f;
    float rs0 = 0.f, rs1 = 0.f, rs2 = 0.f, rs3 = 0.f;

    const int mrow = ((w & 1) * 32 + l31) * 88;

    for (int it = 0; it < NIT; ++it) {
        unsigned short* psc = &ps[it & 1][0];

        // ---- S = Q·K^T with current K regs ----
        const f32x4 z = {0.f, 0.f, 0.f, 0.f};
        __builtin_amdgcn_s_setprio(1);
        f32x4 s0 = __builtin_amdgcn_mfma_f32_16x16x32_bf16(a_q, kr0, z, 0, 0, 0);
        f32x4 s1 = __builtin_amdgcn_mfma_f32_16x16x32_bf16(a_q, kr1, z, 0, 0, 0);
        f32x4 s2 = __builtin_amdgcn_mfma_f32_16x16x32_bf16(a_q, kr2, z, 0, 0, 0);
        f32x4 s3 = __builtin_amdgcn_mfma_f32_16x16x32_bf16(a_q, kr3, z, 0, 0, 0);
        __builtin_amdgcn_s_setprio(0);

        // ---- prefetch next iteration's K into registers ----
        if (it + 1 < NIT) {
            ksrc += 64 * 8;
            if (g == 0) {
                kr0 = *(const bf16x8*)(ksrc);
                kr1 = *(const bf16x8*)(ksrc + 128);
                kr2 = *(const bf16x8*)(ksrc + 256);
                kr3 = *(const bf16x8*)(ksrc + 384);
            }
        }

        // ---- P = exp2(S) (q carries log2e), raw v_exp_f32 ----
        #pragma unroll
        for (int r = 0; r < 4; ++r) {
            const float p0 = __builtin_amdgcn_exp2f(s0[r]);
            const float p1 = __builtin_amdgcn_exp2f(s1[r]);
            const float p2 = __builtin_amdgcn_exp2f(s2[r]);
            const float p3 = __builtin_amdgcn_exp2f(s3[r]);
            const unsigned int lo = __builtin_amdgcn_perm(
                __float_as_uint(p1), __float_as_uint(p0), 0x07060302u);
            const unsigned int hi = __builtin_amdgcn_perm(
                __float_as_uint(p3), __float_as_uint(p2), 0x07060302u);
            *(uint32x2*)&psc[(w * 16 + g * 4 + r) * 88 + 4 * l15] = (uint32x2){lo, hi};
            const float ssum = (p0 + p1) + (p2 + p3);
            if      (r == 0) rs0 += ssum;
            else if (r == 1) rs1 += ssum;
            else if (r == 2) rs2 += ssum;
            else             rs3 += ssum;
        }
        __syncthreads();   // ps[it&1] ready (single barrier per iteration)

        // ---- O^T += V·P^T (4 MFMAs 32x32x16), V straight from registers ----
        __builtin_amdgcn_s_setprio(1);
        {
            const bf16x8 bp0 = *(const bf16x8*)&psc[mrow + 0 * 16 + h * 8];
            oacc = __builtin_amdgcn_mfma_f32_32x32x16_bf16(av0, bp0, oacc, 0, 0, 0);
            const bf16x8 bp1 = *(const bf16x8*)&psc[mrow + 1 * 16 + h * 8];
            oacc = __builtin_amdgcn_mfma_f32_32x32x16_bf16(av1, bp1, oacc, 0, 0, 0);
            const bf16x8 bp2 = *(const bf16x8*)&psc[mrow + 2 * 16 + h * 8];
            oacc = __builtin_amdgcn_mfma_f32_32x32x16_bf16(av2, bp2, oacc, 0, 0, 0);
            const bf16x8 bp3 = *(const bf16x8*)&psc[mrow + 3 * 16 + h * 8];
            oacc = __builtin_amdgcn_mfma_f32_32x32x16_bf16(av3, bp3, oacc, 0, 0, 0);
        }
        __builtin_amdgcn_s_setprio(0);

        // ---- reload V regs for next iter (WAR on av* orders after the MFMAs;
        //      latency hidden under next QK + exp + barrier) ----
        if (it + 1 < NIT) {
            vp += 64;
            av0 = *(const bf16x8*)(vp);
            av1 = *(const bf16x8*)(vp + 16);
            av2 = *(const bf16x8*)(vp + 32);
            av3 = *(const bf16x8*)(vp + 48);
        }
    }

    #pragma unroll
    for (int xm = 1; xm <= 8; xm <<= 1) {
        rs0 += __shfl_xor(rs0, xm);
        rs1 += __shfl_xor(rs1, xm);
        rs2 += __shfl_xor(rs2, xm);
        rs3 += __shfl_xor(rs3, xm);
    }
    if (l15 == 0) {
        float* lp = lpart + (size_t)(p * B + b) * NTOK + m0 + w * 16 + g * 4;
        lp[0] = rs0; lp[1] = rs1; lp[2] = rs2; lp[3] = rs3;
    }
    {
        const int mloc = (w & 1) * 32 + l31;
        #pragma unroll
        for (int reg = 0; reg < 16; ++reg) {
            const int c = (w >> 1) * 32 + (reg & 3) + 8 * (reg >> 2) + 4 * h;
            opart[((size_t)((p * B + b) * CCH + c)) * NTOK + m0 + mloc] =
                f2bf_rne(oacc[reg]);
        }
    }
}

// ---------------------------------------------------------------------------
// Kernel 3: combine NSPLIT partials + normalize + residual (pure streaming).
// ---------------------------------------------------------------------------
__global__ __launch_bounds__(256) void combine_kernel(
    const unsigned short* __restrict__ opart, const float* __restrict__ lpart,
    const float* __restrict__ x, const float* __restrict__ gamma_p,
    float* __restrict__ out, int B)
{
    const float  gm      = gamma_p[0];
    const size_t nf4     = (size_t)B * CCH * NTOK / 4;
    const size_t ostride = (size_t)B * CCH * NTOK;
    for (size_t f = (size_t)blockIdx.x * 256 + threadIdx.x; f < nf4;
         f += (size_t)gridDim.x * 256) {
        const int m4 = ((int)(f & 1023)) * 4;
        const int bc = (int)(f >> 10);
        const int bi = bc >> 6;
        const size_t obase = (size_t)bc * NTOK + m4;

        float4 osum = {0.f, 0.f, 0.f, 0.f};
        float4 lsum = {0.f, 0.f, 0.f, 0.f};
        #pragma unroll
        for (int p = 0; p < NSPLIT; ++p) {
            const ushort4 o = *(const ushort4*)&opart[obase + (size_t)p * ostride];
            const float4  l = *(const float4*)&lpart[(size_t)(p * B + bi) * NTOK + m4];
            osum.x += bf2f(o.x); osum.y += bf2f(o.y);
            osum.z += bf2f(o.z); osum.w += bf2f(o.w);
            lsum.x += l.x; lsum.y += l.y; lsum.z += l.z; lsum.w += l.w;
        }
        const float4 xv = *(const float4*)&x[obase];
        float4 r;
        r.x = osum.x * gm / lsum.x + xv.x;
        r.y = osum.y * gm / lsum.y + xv.y;
        r.z = osum.z * gm / lsum.z + xv.z;
        r.w = osum.w * gm / lsum.w + xv.w;
        *(float4*)&out[obase] = r;
    }
}

extern "C" void kernel_launch(void* const* d_in, const int* in_sizes, int n_in,
                              void* d_out, int out_size, void* d_ws, size_t ws_size,
                              hipStream_t stream) {
    const float* x     = (const float*)d_in[0];
    const float* wq    = (const float*)d_in[1];
    const float* bq    = (const float*)d_in[2];
    const float* wk    = (const float*)d_in[3];
    const float* bk    = (const float*)d_in[4];
    const float* wv    = (const float*)d_in[5];
    const float* bv    = (const float*)d_in[6];
    const float* gamma = (const float*)d_in[7];
    float* out = (float*)d_out;

    int B = in_sizes[0] / (CCH * NTOK);   // 8

    // Workspace: qt | kt (512KB each) | vbf 4MB | opart bf16 16MB | lpart 512KB
    unsigned short* wsp   = (unsigned short*)d_ws;
    unsigned short* qt    = wsp;
    unsigned short* kt    = qt + (size_t)B * NTOK * 8;
    unsigned short* vbf   = kt + (size_t)B * NTOK * 8;
    unsigned short* opart = vbf + (size_t)B * CCH * NTOK;
    float*          lpart = (float*)(opart + (size_t)NSPLIT * B * CCH * NTOK);

    proj_kernel<<<B * 64, 256, 0, stream>>>(x, wq, bq, wk, bk, wv, bv, qt, kt, vbf);
    attn_kernel<<<NSPLIT * B * 64, 256, 0, stream>>>(qt, kt, vbf, opart, lpart, B);
    combine_kernel<<<512, 256, 0, stream>>>(opart, lpart, x, gamma, out, B);
}

// Round 2
// 343.230 us; speedup vs baseline: 1.0136x; 1.0136x over previous
//
#include <hip/hip_runtime.h>
#include <math.h>

#define NTOK 4096
#define CCH  64
#define LOG2E 1.4426950408889634f
#define NSPLIT 4   // KV-split ways

typedef __attribute__((ext_vector_type(8)))  short bf16x8;   // 8 bf16 = 4 VGPRs
typedef __attribute__((ext_vector_type(4)))  float f32x4;
typedef __attribute__((ext_vector_type(16))) float f32x16;
typedef __attribute__((ext_vector_type(2)))  unsigned int uint32x2;

__device__ __forceinline__ unsigned short f2bf_rne(float f) {
    unsigned int u = __float_as_uint(f);
    u += 0x7FFFu + ((u >> 16) & 1u);
    return (unsigned short)(u >> 16);
}
__device__ __forceinline__ float bf2f(unsigned short u) {
    return __uint_as_float(((unsigned int)u) << 16);
}

// ---------------------------------------------------------------------------
// Kernel 1: MFMA projections. One GEMM per (b, 64-token tile):
// D[80x64] = [wv ; wq*log2e ; wk] * x_tile.
// Outputs qt/kt[b][n][8] (q pre-scaled by log2e) and V in FRAGMENT-LINEAR
// layout (round-12 change):
//   vgl[b][tile][kc][h][c][j]  (kc=0..3, h=0..1, c=0..63, j=0..7)
// holding V[c][np = kc*16 + h*8 + j] in the sigma-permuted token order
// (sigma(nu) = 4*(nu&15) + (nu>>4)) that the PV MFMA consumes. This makes
// the attn kernel's per-lane 16B A-fragment loads lane-contiguous
// (c = lane&31 -> consecutive 16B), i.e. fully coalesced — unlike round-11's
// [c][n] layout whose direct loads were 64-lines-per-instruction.
// ---------------------------------------------------------------------------
__global__ __launch_bounds__(256) void proj_kernel(
    const float* __restrict__ x,
    const float* __restrict__ wq, const float* __restrict__ bq,
    const float* __restrict__ wk, const float* __restrict__ bk,
    const float* __restrict__ wv, const float* __restrict__ bv,
    unsigned short* __restrict__ qt, unsigned short* __restrict__ kt,
    unsigned short* __restrict__ vbf)
{
    __shared__ unsigned short xsb[64 * 68];  // [n][c] bf16 (B^T storage)
    __shared__ unsigned short wa[80 * 68];   // [m][c] bf16 (A storage)
    __shared__ unsigned short vtmp[64 * 66]; // [c][sigma(n)]
    __shared__ float bb[80];

    const int t  = threadIdx.x;
    const int b  = blockIdx.x >> 6;
    const int n0 = (blockIdx.x & 63) << 6;

    const int lane = t & 63;
    const int w    = t >> 6;
    const int l15  = lane & 15;
    const int g    = lane >> 4;

    {
        const int n  = t & 63;
        const int c0 = t >> 6;
        #pragma unroll
        for (int r = 0; r < 16; ++r) {
            const int c = c0 + 4 * r;
            xsb[n * 68 + c] = f2bf_rne(x[((size_t)(b * CCH + c)) * NTOK + n0 + n]);
        }
    }
    #pragma unroll
    for (int r = 0; r < 16; ++r) {
        const int i = t + 256 * r;
        wa[(i >> 6) * 68 + (i & 63)] = f2bf_rne(wv[i]);
    }
    {
        const int i0 = t, i1 = t + 256;
        wa[(64 + (i0 >> 6)) * 68 + (i0 & 63)] = f2bf_rne(wq[i0] * LOG2E);
        wa[(64 + (i1 >> 6)) * 68 + (i1 & 63)] = f2bf_rne(wq[i1] * LOG2E);
        wa[(72 + (i0 >> 6)) * 68 + (i0 & 63)] = f2bf_rne(wk[i0]);
        wa[(72 + (i1 >> 6)) * 68 + (i1 & 63)] = f2bf_rne(wk[i1]);
    }
    if (t < 80) {
        float bias;
        if (t < 64)      bias = bv[t];
        else if (t < 72) bias = bq[t - 64] * LOG2E;
        else             bias = bk[t - 72];
        bb[t] = bias;
    }
    __syncthreads();

    f32x4 acc[5];
    #pragma unroll
    for (int mt = 0; mt < 5; ++mt) acc[mt] = (f32x4){0.f, 0.f, 0.f, 0.f};
    #pragma unroll
    for (int kc = 0; kc < 2; ++kc) {
        const bf16x8 bx = *(const bf16x8*)&xsb[(w * 16 + l15) * 68 + kc * 32 + g * 8];
        #pragma unroll
        for (int mt = 0; mt < 5; ++mt) {
            const bf16x8 aw = *(const bf16x8*)&wa[(mt * 16 + l15) * 68 + kc * 32 + g * 8];
            acc[mt] = __builtin_amdgcn_mfma_f32_16x16x32_bf16(aw, bx, acc[mt], 0, 0, 0);
        }
    }

    const int n = w * 16 + l15;
    #pragma unroll
    for (int mt = 0; mt < 4; ++mt) {
        #pragma unroll
        for (int r = 0; r < 4; ++r) {
            const int c = mt * 16 + g * 4 + r;
            vtmp[c * 66 + 4 * l15 + w] = f2bf_rne(acc[mt][r] + bb[c]);
        }
    }
    {
        unsigned short vals[4];
        #pragma unroll
        for (int r = 0; r < 4; ++r)
            vals[r] = f2bf_rne(acc[4][r] + bb[64 + g * 4 + r]);
        const unsigned int lo = (unsigned int)vals[0] | ((unsigned int)vals[1] << 16);
        const unsigned int hi = (unsigned int)vals[2] | ((unsigned int)vals[3] << 16);
        unsigned short* dst = ((g < 2) ? qt : kt) +
                              ((size_t)(b * NTOK + n0 + n)) * 8 + (g & 1) * 4;
        *(uint32x2*)dst = (uint32x2){lo, hi};
    }
    __syncthreads();

    {
        // Fragment-linear V write: c = t&63 (lane-contiguous -> 1KB/instr
        // coalesced stores), q = t>>6 selects the kc quadrant.
        const int c    = t & 63;
        const int q    = t >> 6;
        const int tile = blockIdx.x & 63;
        unsigned short* dst = vbf +
            ((((size_t)((b * 64 + tile) * 4 + q)) * 2 + 0) * 64 + c) * 8;
        *(bf16x8*)dst             = *(const bf16x8*)&vtmp[c * 66 + q * 16];      // h=0
        *(bf16x8*)(dst + 64 * 8)  = *(const bf16x8*)&vtmp[c * 66 + q * 16 + 8]; // h=1
    }
}

// ---------------------------------------------------------------------------
// Kernel 2: MFMA flash attention, KV-split 4 ways. Round-12:
//  1. V A-fragments load DIRECTLY from global in the fragment-linear layout
//     (coalesced, XCD-L2-resident working set: bid%8 == b == XCD id). This
//     removes ALL V traffic from the LDS pipe (was 2 ds_write_b128 +
//     4 ds_read_b128 per wave-iter): LDS per wave-iter 144 -> 72 cyc.
//  2. ps double-buffered (parity it&1) => ONE __syncthreads per iteration.
//     Race-free by induction: a wave writes ps[i&1] again (iter i+2's exp)
//     only after passing barrier(i+1), which requires every wave to have
//     finished PV(i)'s reads of ps[i&1]. LDS total 22528 B (unchanged).
//  3. s_setprio(1) around MFMA clusters (T5).
// ---------------------------------------------------------------------------
__global__ __launch_bounds__(256, 6) void attn_kernel(
    const unsigned short* __restrict__ qt, const unsigned short* __restrict__ kt,
    const unsigned short* __restrict__ vbf,
    unsigned short* __restrict__ opart, float* __restrict__ lpart, int B)
{
    __shared__ unsigned short ps[2][64 * 88];  // [buf][m][n'] bf16 P, dbuf

    const int t    = threadIdx.x;
    const int lane = t & 63;
    const int w    = t >> 6;
    const int bid  = blockIdx.x;
    const int b    = bid % B;                 // == bid & 7 for B=8 -> XCD id
    const int p    = (bid / B) % NSPLIT;
    const int m0   = (bid / (B * NSPLIT)) << 6;

    const int l15 = lane & 15;
    const int g   = lane >> 4;
    const int l31 = lane & 31;
    const int h   = lane >> 5;

    const int NIT     = 64 / NSPLIT;        // 16 KV tiles per block
    const int itStart = p * NIT;

    // ---- Q A-fragment direct from global (k>=8 rows zero) ----
    bf16x8 a_q = {};
    if (g == 0)
        a_q = *(const bf16x8*)&qt[((size_t)(b * NTOK + m0 + w * 16 + l15)) * 8];

    // ---- V A-fragment source, fragment-linear layout:
    //      vgl[b][tile][kc][h][c][j]; lane reads 16B at c = (w>>1)*32 + l31.
    //      Lanes 0..31 (h=0) cover 512B contiguous, lanes 32..63 (h=1) the
    //      adjacent plane: fully coalesced. kc stride = 1024 shorts,
    //      tile stride = 4096 shorts.
    const int cv = (w >> 1) * 32 + l31;
    const unsigned short* vp = vbf +
        ((((size_t)((b * 64 + itStart) * 4)) * 2 + h) * 64 + cv) * 8;

    // ---- K fragment source (only g==0 lanes load; others stay zero) ----
    const unsigned short* ksrc = kt + ((size_t)(b * NTOK + itStart * 64 + l15)) * 8;

    // ---- prefetch iteration 0 ----
    bf16x8 av0 = *(const bf16x8*)(vp);
    bf16x8 av1 = *(const bf16x8*)(vp + 1024);
    bf16x8 av2 = *(const bf16x8*)(vp + 2048);
    bf16x8 av3 = *(const bf16x8*)(vp + 3072);
    bf16x8 kr0 = {}, kr1 = {}, kr2 = {}, kr3 = {};
    if (g == 0) {
        kr0 = *(const bf16x8*)(ksrc);
        kr1 = *(const bf16x8*)(ksrc + 128);   // +16 tokens * 8
        kr2 = *(const bf16x8*)(ksrc + 256);
        kr3 = *(const bf16x8*)(ksrc + 384);
    }

    f32x16 oacc;
    #pragma unroll
    for (int i = 0; i < 16; ++i) oacc[i] = 0.f;
    float rs0 = 0.f, rs1 = 0.f, rs2 = 0.f, rs3 = 0.f;

    const int mrow = ((w & 1) * 32 + l31) * 88;

    for (int it = 0; it < NIT; ++it) {
        unsigned short* psc = &ps[it & 1][0];

        // ---- S = Q·K^T with current K regs ----
        const f32x4 z = {0.f, 0.f, 0.f, 0.f};
        __builtin_amdgcn_s_setprio(1);
        f32x4 s0 = __builtin_amdgcn_mfma_f32_16x16x32_bf16(a_q, kr0, z, 0, 0, 0);
        f32x4 s1 = __builtin_amdgcn_mfma_f32_16x16x32_bf16(a_q, kr1, z, 0, 0, 0);
        f32x4 s2 = __builtin_amdgcn_mfma_f32_16x16x32_bf16(a_q, kr2, z, 0, 0, 0);
        f32x4 s3 = __builtin_amdgcn_mfma_f32_16x16x32_bf16(a_q, kr3, z, 0, 0, 0);
        __builtin_amdgcn_s_setprio(0);

        // ---- prefetch next iteration's K into registers ----
        if (it + 1 < NIT) {
            ksrc += 64 * 8;
            if (g == 0) {
                kr0 = *(const bf16x8*)(ksrc);
                kr1 = *(const bf16x8*)(ksrc + 128);
                kr2 = *(const bf16x8*)(ksrc + 256);
                kr3 = *(const bf16x8*)(ksrc + 384);
            }
        }

        // ---- P = exp2(S) (q carries log2e), raw v_exp_f32 ----
        #pragma unroll
        for (int r = 0; r < 4; ++r) {
            const float p0 = __builtin_amdgcn_exp2f(s0[r]);
            const float p1 = __builtin_amdgcn_exp2f(s1[r]);
            const float p2 = __builtin_amdgcn_exp2f(s2[r]);
            const float p3 = __builtin_amdgcn_exp2f(s3[r]);
            const unsigned int lo = __builtin_amdgcn_perm(
                __float_as_uint(p1), __float_as_uint(p0), 0x07060302u);
            const unsigned int hi = __builtin_amdgcn_perm(
                __float_as_uint(p3), __float_as_uint(p2), 0x07060302u);
            *(uint32x2*)&psc[(w * 16 + g * 4 + r) * 88 + 4 * l15] = (uint32x2){lo, hi};
            const float ssum = (p0 + p1) + (p2 + p3);
            if      (r == 0) rs0 += ssum;
            else if (r == 1) rs1 += ssum;
            else if (r == 2) rs2 += ssum;
            else             rs3 += ssum;
        }
        __syncthreads();   // ps[it&1] ready (single barrier per iteration)

        // ---- O^T += V·P^T (4 MFMAs 32x32x16), V from registers ----
        __builtin_amdgcn_s_setprio(1);
        {
            const bf16x8 bp0 = *(const bf16x8*)&psc[mrow + 0 * 16 + h * 8];
            oacc = __builtin_amdgcn_mfma_f32_32x32x16_bf16(av0, bp0, oacc, 0, 0, 0);
            const bf16x8 bp1 = *(const bf16x8*)&psc[mrow + 1 * 16 + h * 8];
            oacc = __builtin_amdgcn_mfma_f32_32x32x16_bf16(av1, bp1, oacc, 0, 0, 0);
            const bf16x8 bp2 = *(const bf16x8*)&psc[mrow + 2 * 16 + h * 8];
            oacc = __builtin_amdgcn_mfma_f32_32x32x16_bf16(av2, bp2, oacc, 0, 0, 0);
            const bf16x8 bp3 = *(const bf16x8*)&psc[mrow + 3 * 16 + h * 8];
            oacc = __builtin_amdgcn_mfma_f32_32x32x16_bf16(av3, bp3, oacc, 0, 0, 0);
        }
        __builtin_amdgcn_s_setprio(0);

        // ---- reload V regs for next iter (WAR: ordered after the MFMAs;
        //      latency hidden under next QK + exp + barrier) ----
        if (it + 1 < NIT) {
            vp += 4096;
            av0 = *(const bf16x8*)(vp);
            av1 = *(const bf16x8*)(vp + 1024);
            av2 = *(const bf16x8*)(vp + 2048);
            av3 = *(const bf16x8*)(vp + 3072);
        }
    }

    #pragma unroll
    for (int xm = 1; xm <= 8; xm <<= 1) {
        rs0 += __shfl_xor(rs0, xm);
        rs1 += __shfl_xor(rs1, xm);
        rs2 += __shfl_xor(rs2, xm);
        rs3 += __shfl_xor(rs3, xm);
    }
    if (l15 == 0) {
        float* lp = lpart + (size_t)(p * B + b) * NTOK + m0 + w * 16 + g * 4;
        lp[0] = rs0; lp[1] = rs1; lp[2] = rs2; lp[3] = rs3;
    }
    {
        const int mloc = (w & 1) * 32 + l31;
        #pragma unroll
        for (int reg = 0; reg < 16; ++reg) {
            const int c = (w >> 1) * 32 + (reg & 3) + 8 * (reg >> 2) + 4 * h;
            opart[((size_t)((p * B + b) * CCH + c)) * NTOK + m0 + mloc] =
                f2bf_rne(oacc[reg]);
        }
    }
}

// ---------------------------------------------------------------------------
// Kernel 3: combine NSPLIT partials + normalize + residual (pure streaming).
// ---------------------------------------------------------------------------
__global__ __launch_bounds__(256) void combine_kernel(
    const unsigned short* __restrict__ opart, const float* __restrict__ lpart,
    const float* __restrict__ x, const float* __restrict__ gamma_p,
    float* __restrict__ out, int B)
{
    const float  gm      = gamma_p[0];
    const size_t nf4     = (size_t)B * CCH * NTOK / 4;
    const size_t ostride = (size_t)B * CCH * NTOK;
    for (size_t f = (size_t)blockIdx.x * 256 + threadIdx.x; f < nf4;
         f += (size_t)gridDim.x * 256) {
        const int m4 = ((int)(f & 1023)) * 4;
        const int bc = (int)(f >> 10);
        const int bi = bc >> 6;
        const size_t obase = (size_t)bc * NTOK + m4;

        float4 osum = {0.f, 0.f, 0.f, 0.f};
        float4 lsum = {0.f, 0.f, 0.f, 0.f};
        #pragma unroll
        for (int p = 0; p < NSPLIT; ++p) {
            const ushort4 o = *(const ushort4*)&opart[obase + (size_t)p * ostride];
            const float4  l = *(const float4*)&lpart[(size_t)(p * B + bi) * NTOK + m4];
            osum.x += bf2f(o.x); osum.y += bf2f(o.y);
            osum.z += bf2f(o.z); osum.w += bf2f(o.w);
            lsum.x += l.x; lsum.y += l.y; lsum.z += l.z; lsum.w += l.w;
        }
        const float4 xv = *(const float4*)&x[obase];
        float4 r;
        r.x = osum.x * gm / lsum.x + xv.x;
        r.y = osum.y * gm / lsum.y + xv.y;
        r.z = osum.z * gm / lsum.z + xv.z;
        r.w = osum.w * gm / lsum.w + xv.w;
        *(float4*)&out[obase] = r;
    }
}

extern "C" void kernel_launch(void* const* d_in, const int* in_sizes, int n_in,
                              void* d_out, int out_size, void* d_ws, size_t ws_size,
                              hipStream_t stream) {
    const float* x     = (const float*)d_in[0];
    const float* wq    = (const float*)d_in[1];
    const float* bq    = (const float*)d_in[2];
    const float* wk    = (const float*)d_in[3];
    const float* bk    = (const float*)d_in[4];
    const float* wv    = (const float*)d_in[5];
    const float* bv    = (const float*)d_in[6];
    const float* gamma = (const float*)d_in[7];
    float* out = (float*)d_out;

    int B = in_sizes[0] / (CCH * NTOK);   // 8

    // Workspace: qt | kt (512KB each) | vbf 4MB | opart bf16 16MB | lpart 512KB
    unsigned short* wsp   = (unsigned short*)d_ws;
    unsigned short* qt    = wsp;
    unsigned short* kt    = qt + (size_t)B * NTOK * 8;
    unsigned short* vbf   = kt + (size_t)B * NTOK * 8;
    unsigned short* opart = vbf + (size_t)B * CCH * NTOK;
    float*          lpart = (float*)(opart + (size_t)NSPLIT * B * CCH * NTOK);

    proj_kernel<<<B * 64, 256, 0, stream>>>(x, wq, bq, wk, bk, wv, bv, qt, kt, vbf);
    attn_kernel<<<NSPLIT * B * 64, 256, 0, stream>>>(qt, kt, vbf, opart, lpart, B);
    combine_kernel<<<512, 256, 0, stream>>>(opart, lpart, x, gamma, out, B);
}

// Round 3
// 186.704 us; speedup vs baseline: 1.8634x; 1.8384x over previous
//
#include <hip/hip_runtime.h>
#include <math.h>

#define NTOK 4096
#define CCH  64
#define LOG2E 1.4426950408889634f
#define NSPLIT 4   // KV-split ways

typedef __attribute__((ext_vector_type(8)))  short bf16x8;   // 8 bf16 = 4 VGPRs
typedef __attribute__((ext_vector_type(4)))  float f32x4;
typedef __attribute__((ext_vector_type(16))) float f32x16;
typedef __attribute__((ext_vector_type(2)))  unsigned int uint32x2;

__device__ __forceinline__ unsigned short f2bf_rne(float f) {
    unsigned int u = __float_as_uint(f);
    u += 0x7FFFu + ((u >> 16) & 1u);
    return (unsigned short)(u >> 16);
}
__device__ __forceinline__ float bf2f(unsigned short u) {
    return __uint_as_float(((unsigned int)u) << 16);
}

// ---------------------------------------------------------------------------
// Kernel 1: MFMA projections (round-5 proven, byte-identical to the 52.6us
// round-0 version). One GEMM per (b, 64-token tile):
// D[80x64] = [wv ; wq*log2e ; wk] * x_tile.
// Outputs qt/kt[b][n][8] (q pre-scaled by log2e) and
// vbf[b][c][tile*64 + sigma(nu)], sigma(nu) = 4*(nu&15) + (nu>>4).
// ---------------------------------------------------------------------------
__global__ __launch_bounds__(256) void proj_kernel(
    const float* __restrict__ x,
    const float* __restrict__ wq, const float* __restrict__ bq,
    const float* __restrict__ wk, const float* __restrict__ bk,
    const float* __restrict__ wv, const float* __restrict__ bv,
    unsigned short* __restrict__ qt, unsigned short* __restrict__ kt,
    unsigned short* __restrict__ vbf)
{
    __shared__ unsigned short xsb[64 * 68];  // [n][c] bf16 (B^T storage)
    __shared__ unsigned short wa[80 * 68];   // [m][c] bf16 (A storage)
    __shared__ unsigned short vtmp[64 * 66]; // [c][sigma(n)]
    __shared__ float bb[80];

    const int t  = threadIdx.x;
    const int b  = blockIdx.x >> 6;
    const int n0 = (blockIdx.x & 63) << 6;

    const int lane = t & 63;
    const int w    = t >> 6;
    const int l15  = lane & 15;
    const int g    = lane >> 4;

    {
        const int n  = t & 63;
        const int c0 = t >> 6;
        #pragma unroll
        for (int r = 0; r < 16; ++r) {
            const int c = c0 + 4 * r;
            xsb[n * 68 + c] = f2bf_rne(x[((size_t)(b * CCH + c)) * NTOK + n0 + n]);
        }
    }
    #pragma unroll
    for (int r = 0; r < 16; ++r) {
        const int i = t + 256 * r;
        wa[(i >> 6) * 68 + (i & 63)] = f2bf_rne(wv[i]);
    }
    {
        const int i0 = t, i1 = t + 256;
        wa[(64 + (i0 >> 6)) * 68 + (i0 & 63)] = f2bf_rne(wq[i0] * LOG2E);
        wa[(64 + (i1 >> 6)) * 68 + (i1 & 63)] = f2bf_rne(wq[i1] * LOG2E);
        wa[(72 + (i0 >> 6)) * 68 + (i0 & 63)] = f2bf_rne(wk[i0]);
        wa[(72 + (i1 >> 6)) * 68 + (i1 & 63)] = f2bf_rne(wk[i1]);
    }
    if (t < 80) {
        float bias;
        if (t < 64)      bias = bv[t];
        else if (t < 72) bias = bq[t - 64] * LOG2E;
        else             bias = bk[t - 72];
        bb[t] = bias;
    }
    __syncthreads();

    f32x4 acc[5];
    #pragma unroll
    for (int mt = 0; mt < 5; ++mt) acc[mt] = (f32x4){0.f, 0.f, 0.f, 0.f};
    #pragma unroll
    for (int kc = 0; kc < 2; ++kc) {
        const bf16x8 bx = *(const bf16x8*)&xsb[(w * 16 + l15) * 68 + kc * 32 + g * 8];
        #pragma unroll
        for (int mt = 0; mt < 5; ++mt) {
            const bf16x8 aw = *(const bf16x8*)&wa[(mt * 16 + l15) * 68 + kc * 32 + g * 8];
            acc[mt] = __builtin_amdgcn_mfma_f32_16x16x32_bf16(aw, bx, acc[mt], 0, 0, 0);
        }
    }

    const int n = w * 16 + l15;
    #pragma unroll
    for (int mt = 0; mt < 4; ++mt) {
        #pragma unroll
        for (int r = 0; r < 4; ++r) {
            const int c = mt * 16 + g * 4 + r;
            vtmp[c * 66 + 4 * l15 + w] = f2bf_rne(acc[mt][r] + bb[c]);
        }
    }
    {
        unsigned short vals[4];
        #pragma unroll
        for (int r = 0; r < 4; ++r)
            vals[r] = f2bf_rne(acc[4][r] + bb[64 + g * 4 + r]);
        const unsigned int lo = (unsigned int)vals[0] | ((unsigned int)vals[1] << 16);
        const unsigned int hi = (unsigned int)vals[2] | ((unsigned int)vals[3] << 16);
        unsigned short* dst = ((g < 2) ? qt : kt) +
                              ((size_t)(b * NTOK + n0 + n)) * 8 + (g & 1) * 4;
        *(uint32x2*)dst = (uint32x2){lo, hi};
    }
    __syncthreads();

    {
        const int c = t >> 2;
        const int q = t & 3;
        unsigned short* dst = vbf + ((size_t)(b * CCH + c)) * NTOK + n0 + q * 16;
        *(bf16x8*)dst       = *(const bf16x8*)&vtmp[c * 66 + q * 16];
        *(bf16x8*)(dst + 8) = *(const bf16x8*)&vtmp[c * 66 + q * 16 + 8];
    }
}

// ---------------------------------------------------------------------------
// Kernel 2: MFMA flash attention, KV-split 4 ways. Round-13: REVERT to the
// proven round-0 LDS-staged structure (direct-from-global V in r11/r12
// collapsed cross-block L2 reuse: FETCH 7.2->265MB, WRITE 29->502MB —
// per-block-unique-footprint fetch, write-combining destroyed). Changes vs
// round-0 (52.6us), each independently low-risk:
//  1. BOTH vs and ps double-buffered (parity it&1) => ONE __syncthreads per
//     iteration (r0 had two). WAR safety by induction: a wave overwrites
//     vs/ps[i&1] next at iter i+2, only after passing barrier(i+1); every
//     wave reaches barrier(i+1) after its PV(i) ds_reads drained (compiler
//     emits s_waitcnt lgkmcnt(0) before s_barrier).
//  2. LDS 22528 -> 45056 B caps 3 blocks/CU == r0's measured effective
//     occupancy (~40% = 3.2 blocks), so occupancy is a wash.
//  3. s_setprio(1) around MFMA clusters (T5: pays when waves/blocks are
//     phase-staggered, which single-barrier + 3 blocks/CU provides).
// ---------------------------------------------------------------------------
__global__ __launch_bounds__(256, 3) void attn_kernel(
    const unsigned short* __restrict__ qt, const unsigned short* __restrict__ kt,
    const unsigned short* __restrict__ vbf,
    unsigned short* __restrict__ opart, float* __restrict__ lpart, int B)
{
    __shared__ unsigned short vs[2][64 * 88];  // [buf][c][n'] pre-permuted V
    __shared__ unsigned short ps[2][64 * 88];  // [buf][m][n'] bf16 P

    const int t    = threadIdx.x;
    const int lane = t & 63;
    const int w    = t >> 6;
    const int bid  = blockIdx.x;
    const int b    = bid % B;                 // == bid & 7 for B=8 -> XCD id
    const int p    = (bid / B) % NSPLIT;
    const int m0   = (bid / (B * NSPLIT)) << 6;

    const int l15 = lane & 15;
    const int g   = lane >> 4;
    const int l31 = lane & 31;
    const int h   = lane >> 5;

    const int NIT     = 64 / NSPLIT;        // 16 KV tiles per block
    const int itStart = p * NIT;

    // ---- Q A-fragment direct from global (k>=8 rows zero) ----
    bf16x8 a_q = {};
    if (g == 0)
        a_q = *(const bf16x8*)&qt[((size_t)(b * NTOK + m0 + w * 16 + l15)) * 8];

    // ---- per-thread V staging pointers (two 16B chunks per thread) ----
    const int c0  = t >> 3, seg = t & 7;
    const int c1  = c0 + 32;
    const unsigned short* vsrc0 = vbf + ((size_t)(b * CCH + c0)) * NTOK
                                      + itStart * 64 + seg * 8;
    const unsigned short* vsrc1 = vbf + ((size_t)(b * CCH + c1)) * NTOK
                                      + itStart * 64 + seg * 8;
    const int voff0 = c0 * 88 + seg * 8;     // offset within vs[buf]
    const int voff1 = c1 * 88 + seg * 8;

    // ---- K fragment source (only g==0 lanes load; others stay zero) ----
    const unsigned short* ksrc = kt + ((size_t)(b * NTOK + itStart * 64 + l15)) * 8;

    // ---- prefetch iteration 0 ----
    bf16x8 vreg0 = *(const bf16x8*)vsrc0;
    bf16x8 vreg1 = *(const bf16x8*)vsrc1;
    bf16x8 kr0 = {}, kr1 = {}, kr2 = {}, kr3 = {};
    if (g == 0) {
        kr0 = *(const bf16x8*)(ksrc);
        kr1 = *(const bf16x8*)(ksrc + 128);   // +16 tokens * 8
        kr2 = *(const bf16x8*)(ksrc + 256);
        kr3 = *(const bf16x8*)(ksrc + 384);
    }

    f32x16 oacc;
    #pragma unroll
    for (int i = 0; i < 16; ++i) oacc[i] = 0.f;
    float rs0 = 0.f, rs1 = 0.f, rs2 = 0.f, rs3 = 0.f;

    const int crow = ((w >> 1) * 32 + l31) * 88;
    const int mrow = ((w & 1) * 32 + l31) * 88;

    for (int it = 0; it < NIT; ++it) {
        unsigned short* vsc = &vs[it & 1][0];
        unsigned short* psc = &ps[it & 1][0];

        // ---- commit prefetched V tile to vs[it&1] (safe: prev use of this
        //      buffer drained before barrier(it-1)) ----
        *(bf16x8*)(vsc + voff0) = vreg0;
        *(bf16x8*)(vsc + voff1) = vreg1;

        // ---- S = Q·K^T with current K regs ----
        const f32x4 z = {0.f, 0.f, 0.f, 0.f};
        __builtin_amdgcn_s_setprio(1);
        f32x4 s0 = __builtin_amdgcn_mfma_f32_16x16x32_bf16(a_q, kr0, z, 0, 0, 0);
        f32x4 s1 = __builtin_amdgcn_mfma_f32_16x16x32_bf16(a_q, kr1, z, 0, 0, 0);
        f32x4 s2 = __builtin_amdgcn_mfma_f32_16x16x32_bf16(a_q, kr2, z, 0, 0, 0);
        f32x4 s3 = __builtin_amdgcn_mfma_f32_16x16x32_bf16(a_q, kr3, z, 0, 0, 0);
        __builtin_amdgcn_s_setprio(0);

        // ---- prefetch next iteration's V + K into registers ----
        if (it + 1 < NIT) {
            vsrc0 += 64;  vsrc1 += 64;  ksrc += 64 * 8;
            vreg0 = *(const bf16x8*)vsrc0;
            vreg1 = *(const bf16x8*)vsrc1;
            if (g == 0) {
                kr0 = *(const bf16x8*)(ksrc);
                kr1 = *(const bf16x8*)(ksrc + 128);
                kr2 = *(const bf16x8*)(ksrc + 256);
                kr3 = *(const bf16x8*)(ksrc + 384);
            }
        }

        // ---- P = exp2(S) (q carries log2e), raw v_exp_f32 ----
        #pragma unroll
        for (int r = 0; r < 4; ++r) {
            const float p0 = __builtin_amdgcn_exp2f(s0[r]);
            const float p1 = __builtin_amdgcn_exp2f(s1[r]);
            const float p2 = __builtin_amdgcn_exp2f(s2[r]);
            const float p3 = __builtin_amdgcn_exp2f(s3[r]);
            const unsigned int lo = __builtin_amdgcn_perm(
                __float_as_uint(p1), __float_as_uint(p0), 0x07060302u);
            const unsigned int hi = __builtin_amdgcn_perm(
                __float_as_uint(p3), __float_as_uint(p2), 0x07060302u);
            *(uint32x2*)&psc[(w * 16 + g * 4 + r) * 88 + 4 * l15] = (uint32x2){lo, hi};
            const float ssum = (p0 + p1) + (p2 + p3);
            if      (r == 0) rs0 += ssum;
            else if (r == 1) rs1 += ssum;
            else if (r == 2) rs2 += ssum;
            else             rs3 += ssum;
        }
        __syncthreads();   // vs[it&1] + ps[it&1] ready (single barrier/iter)

        // ---- O^T += V·P^T (4 MFMAs 32x32x16) ----
        __builtin_amdgcn_s_setprio(1);
        #pragma unroll
        for (int kc = 0; kc < 4; ++kc) {
            const bf16x8 a_v = *(const bf16x8*)&vsc[crow + kc * 16 + h * 8];
            const bf16x8 b_p = *(const bf16x8*)&psc[mrow + kc * 16 + h * 8];
            oacc = __builtin_amdgcn_mfma_f32_32x32x16_bf16(a_v, b_p, oacc, 0, 0, 0);
        }
        __builtin_amdgcn_s_setprio(0);
    }

    #pragma unroll
    for (int xm = 1; xm <= 8; xm <<= 1) {
        rs0 += __shfl_xor(rs0, xm);
        rs1 += __shfl_xor(rs1, xm);
        rs2 += __shfl_xor(rs2, xm);
        rs3 += __shfl_xor(rs3, xm);
    }
    if (l15 == 0) {
        float* lp = lpart + (size_t)(p * B + b) * NTOK + m0 + w * 16 + g * 4;
        lp[0] = rs0; lp[1] = rs1; lp[2] = rs2; lp[3] = rs3;
    }
    {
        const int mloc = (w & 1) * 32 + l31;
        #pragma unroll
        for (int reg = 0; reg < 16; ++reg) {
            const int c = (w >> 1) * 32 + (reg & 3) + 8 * (reg >> 2) + 4 * h;
            opart[((size_t)((p * B + b) * CCH + c)) * NTOK + m0 + mloc] =
                f2bf_rne(oacc[reg]);
        }
    }
}

// ---------------------------------------------------------------------------
// Kernel 3: combine NSPLIT partials + normalize + residual (pure streaming).
// ---------------------------------------------------------------------------
__global__ __launch_bounds__(256) void combine_kernel(
    const unsigned short* __restrict__ opart, const float* __restrict__ lpart,
    const float* __restrict__ x, const float* __restrict__ gamma_p,
    float* __restrict__ out, int B)
{
    const float  gm      = gamma_p[0];
    const size_t nf4     = (size_t)B * CCH * NTOK / 4;
    const size_t ostride = (size_t)B * CCH * NTOK;
    for (size_t f = (size_t)blockIdx.x * 256 + threadIdx.x; f < nf4;
         f += (size_t)gridDim.x * 256) {
        const int m4 = ((int)(f & 1023)) * 4;
        const int bc = (int)(f >> 10);
        const int bi = bc >> 6;
        const size_t obase = (size_t)bc * NTOK + m4;

        float4 osum = {0.f, 0.f, 0.f, 0.f};
        float4 lsum = {0.f, 0.f, 0.f, 0.f};
        #pragma unroll
        for (int p = 0; p < NSPLIT; ++p) {
            const ushort4 o = *(const ushort4*)&opart[obase + (size_t)p * ostride];
            const float4  l = *(const float4*)&lpart[(size_t)(p * B + bi) * NTOK + m4];
            osum.x += bf2f(o.x); osum.y += bf2f(o.y);
            osum.z += bf2f(o.z); osum.w += bf2f(o.w);
            lsum.x += l.x; lsum.y += l.y; lsum.z += l.z; lsum.w += l.w;
        }
        const float4 xv = *(const float4*)&x[obase];
        float4 r;
        r.x = osum.x * gm / lsum.x + xv.x;
        r.y = osum.y * gm / lsum.y + xv.y;
        r.z = osum.z * gm / lsum.z + xv.z;
        r.w = osum.w * gm / lsum.w + xv.w;
        *(float4*)&out[obase] = r;
    }
}

extern "C" void kernel_launch(void* const* d_in, const int* in_sizes, int n_in,
                              void* d_out, int out_size, void* d_ws, size_t ws_size,
                              hipStream_t stream) {
    const float* x     = (const float*)d_in[0];
    const float* wq    = (const float*)d_in[1];
    const float* bq    = (const float*)d_in[2];
    const float* wk    = (const float*)d_in[3];
    const float* bk    = (const float*)d_in[4];
    const float* wv    = (const float*)d_in[5];
    const float* bv    = (const float*)d_in[6];
    const float* gamma = (const float*)d_in[7];
    float* out = (float*)d_out;

    int B = in_sizes[0] / (CCH * NTOK);   // 8

    // Workspace: qt | kt (512KB each) | vbf 4MB | opart bf16 16MB | lpart 512KB
    unsigned short* wsp   = (unsigned short*)d_ws;
    unsigned short* qt    = wsp;
    unsigned short* kt    = qt + (size_t)B * NTOK * 8;
    unsigned short* vbf   = kt + (size_t)B * NTOK * 8;
    unsigned short* opart = vbf + (size_t)B * CCH * NTOK;
    float*          lpart = (float*)(opart + (size_t)NSPLIT * B * CCH * NTOK);

    proj_kernel<<<B * 64, 256, 0, stream>>>(x, wq, bq, wk, bk, wv, bv, qt, kt, vbf);
    attn_kernel<<<NSPLIT * B * 64, 256, 0, stream>>>(qt, kt, vbf, opart, lpart, B);
    combine_kernel<<<512, 256, 0, stream>>>(opart, lpart, x, gamma, out, B);
}